// Round 16
// baseline (17.375 us; speedup 1.0000x reference)
//
#include <hip/hip_runtime.h>
#include <math.h>

// Duhamel layer == per-channel causal FIR, h[q] = (1/wD) r^q sin(q*theta).
// Exact one-stream form: e[k] = (x[k] - g^W x[k-W])/wD;  Z = g Z + e;  y = Im Z.
// ALL-CHANNELS-ONE-STAGE + WAVE-AUTONOMOUS STORES + 2 BLOCKS/CU:
//   block = (batch, 2048-chunk); stage x window once (23.8 KB swizzled tile);
//   wave o = channel o with per-channel halo; 2 sub-rounds x 1024 outputs:
//   IIR (16/lane, lz in regs) -> wave shfl scan -> exact seed -> correct ->
//   transpose via PRIVATE 4 KB ybuf slice (wave-local, no block barrier) ->
//   per-wave coalesced 1KB stores.  Single __syncthreads (after stage).
//   512 blocks = exactly 2/CU (16 waves/CU), one generation, zero tail.

#define N_SAMP  65536
#define NB      16
#define NO      8
#define NT      512
#define LBLK    2048          // outputs per block per channel
#define LOOKB   3904          // ch0 halo 2048 + 1844 rounded to mult 32
#define TQ      1488          // tile quads ((2048+3904)/4) = 23.8 KB

constexpr int CW[NO]  = {1844, 1317, 1024, 768, 576, 419, 307, 230};
// per-lane halo samples (mult of 4): alpha*64*hseg >= 5.1 per channel
constexpr int CHS[NO] = {32, 24, 20, 16, 12, 8, 8, 4};

// XOR quad swizzle (involution within 8-quad groups): breaks stride-bank
// alignment of per-lane quad access.
__device__ __forceinline__ int P(int q) { return q ^ ((q >> 3) & 7); }

__device__ __forceinline__ float rfl(float x) {
    return __int_as_float(__builtin_amdgcn_readfirstlane(__float_as_int(x)));
}

template<int O>
__device__ __forceinline__ void duh_wave(const float* __restrict__ lw,
                                         float* __restrict__ out,
                                         const float* __restrict__ tile,
                                         float* __restrict__ yw,   // 4KB slice
                                         int b, int n0, int lane)
{
    constexpr int W  = CW[O];
    constexpr int Wu = (W + 3) & ~3;
    constexpr int E  = Wu - W;               // 0..3 intra-quad shift
    constexpr int QW = Wu / 4;               // delayed quad offset
    constexpr int HS = CHS[O];               // halo samples per lane
    constexpr int HQ = HS / 4;               // halo quads per lane

    // ---- per-wave channel constants (fast transcendentals) -> SGPR ---------
    const float omf  = fminf(fmaxf(__expf(lw[O]), 0.01f), 1000.0f);
    const float omD  = omf * 0.99874921777190895f;    // sqrt(1-0.05^2)
    const float th   = omD * 0.01f;
    const float alph = 0.0005f * omf;
    const float r1   = __expf(-alph);
    const float gr = rfl(r1 * __cosf(th)), gi = rfl(r1 * __sinf(th));   // g
    const float rW   = __expf(-alph * (float)W);
    const float aW   = th * (float)W;
    const float binv = 1.0f / omD;
    const float c1   = rfl(binv);
    const float c2   = rfl(binv * rW * __cosf(aW));    //  binv*Re g^W
    const float cei  = rfl(-binv * rW * __sinf(aW));   // -binv*Im g^W

    // G2..G4 for store correction
    float g2r_ = gr*gr - gi*gi,         g2i_ = 2.f*gr*gi;
    float g3r_ = g2r_*gr - g2i_*gi,     g3i_ = g2r_*gi + g2i_*gr;
    float g4r_ = g2r_*g2r_ - g2i_*g2i_, g4i_ = 2.f*g2r_*g2i_;
    const float G2r = rfl(g2r_), G2i = rfl(g2i_);
    const float G3r = rfl(g3r_), G3i = rfl(g3i_);
    const float G4r = rfl(g4r_), G4i = rfl(g4i_);

    // Mo[k] = g^(16*2^k) k=0..6  (out scan; Mo[6] = g^1024 carry multiplier)
    float Mor[7], Moi[7];
    {
        const float rl = __expf(-alph * 16.f);
        const float al = th * 16.f;
        float pr = rl * __cosf(al), pq = rl * __sinf(al);
#pragma unroll
        for (int k = 0; k < 7; ++k) {
            Mor[k] = rfl(pr); Moi[k] = rfl(pq);
            const float nr = pr*pr - pq*pq, ni = 2.f*pr*pq;
            pr = nr; pq = ni;
        }
    }
    // Mh[k] = g^(HS*2^k) k=0..5  (halo scan)
    float Mhr[6], Mhi[6];
    {
        const float rl = __expf(-alph * (float)HS);
        const float al = th * (float)HS;
        float pr = rl * __cosf(al), pq = rl * __sinf(al);
#pragma unroll
        for (int k = 0; k < 6; ++k) {
            Mhr[k] = rfl(pr); Mhi[k] = rfl(pq);
            const float nr = pr*pr - pq*pq, ni = 2.f*pr*pq;
            pr = nr; pq = ni;
        }
    }
    // pl = g^(16*lane)
    float plr = 1.f, pli = 0.f;
#pragma unroll
    for (int k = 0; k < 6; ++k) {
        if ((lane >> k) & 1) {
            const float nr = plr*Mor[k] - pli*Moi[k];
            const float ni = plr*Moi[k] + pli*Mor[k];
            plr = nr; pli = ni;
        }
    }

#define LDQ(q) (*(const float4*)&tile[4 * P(q)])
#define DSEL(e0,e1,e2,e3,d0,dn)                                              \
    if constexpr (E == 0)      { e0=d0.x; e1=d0.y; e2=d0.z; e3=d0.w; }       \
    else if constexpr (E == 1) { e0=d0.y; e1=d0.z; e2=d0.w; e3=dn.x; }       \
    else if constexpr (E == 2) { e0=d0.z; e1=d0.w; e2=dn.x; e3=dn.y; }       \
    else                       { e0=d0.w; e1=dn.x; e2=dn.y; e3=dn.z; }
#define STEP(xa, xc)                                              \
    {                                                             \
        const float er = fmaf(-c2, (xc), c1 * (xa));              \
        const float ei = cei * (xc);                              \
        const float nr = fmaf(gr, Br, fmaf(-gi, Bi, er));         \
        const float ni = fmaf(gi, Br, fmaf( gr, Bi, ei));         \
        Br = nr; Bi = ni;                                         \
    }

    // ---------------- halo: HS samples/lane, total only ---------------------
    float Cr, Ci;
    {
        float Br = 0.f, Bi = 0.f;
        const int q1 = 976 - 16 * HS + HQ * lane;   // covers [n0-64*HS, n0)
        const int q2 = q1 - QW;
        float4 d0 = LDQ(q2);
#pragma unroll
        for (int m = 0; m < HQ; ++m) {
            const float4 s1 = LDQ(q1 + m);
            const float4 dn = LDQ(q2 + m + 1);
            float e0, e1, e2, e3;
            DSEL(e0, e1, e2, e3, d0, dn);
            STEP(s1.x, e0); STEP(s1.y, e1); STEP(s1.z, e2); STEP(s1.w, e3);
            d0 = dn;
        }
        float Sr = Br, Si = Bi;
#pragma unroll
        for (int k = 0; k < 6; ++k) {
            const int d = 1 << k;
            const float ur = __shfl_up(Sr, d, 64);
            const float ui = __shfl_up(Si, d, 64);
            if (lane >= d) {
                const float nr = fmaf(Mhr[k], ur, fmaf(-Mhi[k], ui, Sr));
                const float ni = fmaf(Mhr[k], ui, fmaf( Mhi[k], ur, Si));
                Sr = nr; Si = ni;
            }
        }
        Cr = rfl(__shfl(Sr, 63, 64));       // exact state at n0 (zero-seeded)
        Ci = rfl(__shfl(Si, 63, 64));
    }

    // ---------------- 2 out sub-rounds x 1024 samples -----------------------
#pragma unroll
    for (int s = 0; s < 2; ++s) {
        const int q1 = 976 + 256 * s + 4 * lane;
        const int q2 = q1 - QW;

        float4 lz[4];
        float Br = 0.f, Bi = 0.f;
        float4 d0 = LDQ(q2);
#pragma unroll
        for (int m = 0; m < 4; ++m) {
            const float4 s1 = LDQ(q1 + m);
            const float4 dn = LDQ(q2 + m + 1);
            float e0, e1, e2, e3;
            DSEL(e0, e1, e2, e3, d0, dn);
            float4 lq;
            STEP(s1.x, e0); lq.x = Bi;
            STEP(s1.y, e1); lq.y = Bi;
            STEP(s1.z, e2); lq.z = Bi;
            STEP(s1.w, e3); lq.w = Bi;
            lz[m] = lq;
            d0 = dn;
        }

        // wave inclusive affine scan (segment mult g^16)
        float Sr = Br, Si = Bi;
#pragma unroll
        for (int k = 0; k < 6; ++k) {
            const int d = 1 << k;
            const float ur = __shfl_up(Sr, d, 64);
            const float ui = __shfl_up(Si, d, 64);
            if (lane >= d) {
                const float nr = fmaf(Mor[k], ur, fmaf(-Moi[k], ui, Sr));
                const float ni = fmaf(Mor[k], ui, fmaf( Moi[k], ur, Si));
                Sr = nr; Si = ni;
            }
        }
        const float Tr = __shfl(Sr, 63, 64);
        const float Ti = __shfl(Si, 63, 64);
        float exr = __shfl_up(Sr, 1, 64);
        float exi = __shfl_up(Si, 1, 64);
        if (lane == 0) { exr = 0.f; exi = 0.f; }

        // exact seed entering this lane's 16-sample segment
        const float sr = fmaf(plr, Cr, fmaf(-pli, Ci, exr));
        const float si = fmaf(plr, Ci, fmaf( pli, Cr, exi));

        // correct + transpose through private ybuf slice (wave-local)
        float wr = fmaf(gr, sr, -(gi * si));    // w = g * seed
        float wi = fmaf(gi, sr,  (gr * si));
#pragma unroll
        for (int m = 0; m < 4; ++m) {
            float4 y;
            y.x = lz[m].x + wi;
            y.y = fmaf(gi,  wr, fmaf(gr,  wi, lz[m].y));
            y.z = fmaf(G2i, wr, fmaf(G2r, wi, lz[m].z));
            y.w = fmaf(G3i, wr, fmaf(G3r, wi, lz[m].w));
            *(float4*)&yw[4 * P(4 * lane + m)] = y;
            const float nwr = fmaf(G4r, wr, -(G4i * wi));
            const float nwi = fmaf(G4i, wr,  (G4r * wi));
            wr = nwr; wi = nwi;
        }
        // per-wave coalesced store (1 KB contiguous per instruction);
        // same-wave LDS write->read: compiler inserts the lgkmcnt wait.
        float* op = out + ((size_t)(b * NO + O)) * (size_t)N_SAMP
                        + n0 + s * 1024;
#pragma unroll
        for (int i = 0; i < 4; ++i) {
            const int q = 64 * i + lane;
            const float4 v = *(const float4*)&yw[4 * P(q)];
            *(float4*)(op + 4 * q) = v;
        }

        // carry: C = g^1024 * C + T
        const float nCr = fmaf(Mor[6], Cr, fmaf(-Moi[6], Ci, Tr));
        const float nCi = fmaf(Mor[6], Ci, fmaf( Moi[6], Cr, Ti));
        Cr = rfl(nCr); Ci = rfl(nCi);
    }
#undef STEP
#undef DSEL
#undef LDQ
}

__global__ __launch_bounds__(NT, 4)
void duh_kernel(const float* __restrict__ x, const float* __restrict__ lw,
                float* __restrict__ out)
{
    __shared__ float tile[TQ * 4];            // 23,808 B
    __shared__ float ybuf[NO * 1024];         // 32 KB: 4 KB per wave
    const int c  = blockIdx.x;
    const int b  = blockIdx.y;
    const int n0 = c * LBLK;
    const int t  = threadIdx.x;

    // ---- cooperative coalesced stage: [n0-3904, n0+2048) -------------------
    const float* xb = x + (size_t)b * N_SAMP;
    const int tstart = n0 - LOOKB;
#pragma unroll
    for (int i = 0; i < 3; ++i) {
        const int k = t + 512 * i;
        if (k < TQ) {
            const int g0 = tstart + 4 * k;    // mult of 4; quad fully in/out
            float4 v;
            if (g0 >= 0) v = *(const float4*)(xb + g0);
            else { v.x = 0.f; v.y = 0.f; v.z = 0.f; v.w = 0.f; }
            *(float4*)&tile[4 * P(k)] = v;
        }
    }
    __syncthreads();                           // the ONLY block barrier

    const int wv   = t >> 6;
    const int lane = t & 63;
    float* yw = ybuf + wv * 1024;
    switch (wv) {                              // wave o <-> channel o
      case 0: duh_wave<0>(lw, out, tile, yw, b, n0, lane); break;
      case 1: duh_wave<1>(lw, out, tile, yw, b, n0, lane); break;
      case 2: duh_wave<2>(lw, out, tile, yw, b, n0, lane); break;
      case 3: duh_wave<3>(lw, out, tile, yw, b, n0, lane); break;
      case 4: duh_wave<4>(lw, out, tile, yw, b, n0, lane); break;
      case 5: duh_wave<5>(lw, out, tile, yw, b, n0, lane); break;
      case 6: duh_wave<6>(lw, out, tile, yw, b, n0, lane); break;
      default:duh_wave<7>(lw, out, tile, yw, b, n0, lane); break;
    }
}

extern "C" void kernel_launch(void* const* d_in, const int* in_sizes, int n_in,
                              void* d_out, int out_size, void* d_ws, size_t ws_size,
                              hipStream_t stream) {
    const float* x  = (const float*)d_in[0];
    const float* lw = (const float*)d_in[1];
    float* out = (float*)d_out;

    dim3 grid(N_SAMP / LBLK, NB);   // 32 chunks x 16 batches = 512 blocks
    duh_kernel<<<grid, dim3(NT), 0, stream>>>(x, lw, out);
}

// Round 18
// 16.957 us; speedup vs baseline: 1.0247x; 1.0247x over previous
//
#include <hip/hip_runtime.h>
#include <math.h>

// Duhamel layer == per-channel causal FIR, h[q] = (1/wD) r^q sin(q*theta).
// Exact one-stream form: e[k] = (x[k] - g^W x[k-W])/wD;  Z = g Z + e;  y = Im Z.
// ALL-CHANNELS-ONE-STAGE + 16 INDEPENDENT WAVES + r16-verified sub-rounds:
//   block = (batch, 4096-chunk): stage x window ONCE (32 KB, swizzled).
//   wave (o,s) = channel o, half s: OWN per-channel halo back from n0+s*2048;
//   then TWO 1024-sample sub-rounds (16 samples/lane, wave shfl scan, exact
//   seed, serial carry C = g^1024 C + T), correction fused, transpose via
//   PRIVATE 4 KB ybuf slice (wave-local), per-wave coalesced 1 KB stores.
//   Single __syncthreads (after stage).  256 blocks x 1024 thr = 1 block/CU.

#define N_SAMP  65536
#define NB      16
#define NO      8
#define NT      1024
#define LBLK    4096          // outputs per block per channel
#define LOOKB   3904          // ch0 halo 2048 + 1844 rounded to mult 32
#define TQ      2000          // tile quads (8000 floats = 32 KB)

constexpr int CW[NO]  = {1844, 1317, 1024, 768, 576, 419, 307, 230};
// per-lane halo samples (mult of 4): alpha*64*hseg >= 5.1 per channel
constexpr int CHS[NO] = {32, 24, 20, 16, 12, 8, 8, 4};

// XOR quad swizzle (involution within 8-quad groups): breaks stride-bank
// alignment of per-lane quad access.
__device__ __forceinline__ int P(int q) { return q ^ ((q >> 3) & 7); }

__device__ __forceinline__ float rfl(float x) {
    return __int_as_float(__builtin_amdgcn_readfirstlane(__float_as_int(x)));
}

template<int O>
__device__ __forceinline__ void duh_wave(const float* __restrict__ lw,
                                         float* __restrict__ out,
                                         const float* __restrict__ tile,
                                         float* __restrict__ yw,   // 4KB slice
                                         int b, int n0, int s, int lane)
{
    constexpr int W  = CW[O];
    constexpr int Wu = (W + 3) & ~3;
    constexpr int E  = Wu - W;               // 0..3 intra-quad shift
    constexpr int QW = Wu / 4;               // delayed quad offset
    constexpr int HS = CHS[O];               // halo samples per lane
    constexpr int HQ = HS / 4;               // halo quads per lane

    // ---- per-wave channel constants (fast transcendentals) -> SGPR ---------
    const float omf  = fminf(fmaxf(__expf(lw[O]), 0.01f), 1000.0f);
    const float omD  = omf * 0.99874921777190895f;    // sqrt(1-0.05^2)
    const float th   = omD * 0.01f;
    const float alph = 0.0005f * omf;
    const float r1   = __expf(-alph);
    const float gr = rfl(r1 * __cosf(th)), gi = rfl(r1 * __sinf(th));   // g
    const float rW   = __expf(-alph * (float)W);
    const float aW   = th * (float)W;
    const float binv = 1.0f / omD;
    const float c1   = rfl(binv);
    const float c2   = rfl(binv * rW * __cosf(aW));    //  binv*Re g^W
    const float cei  = rfl(-binv * rW * __sinf(aW));   // -binv*Im g^W

    // G2..G4 for store correction
    float g2r_ = gr*gr - gi*gi,         g2i_ = 2.f*gr*gi;
    float g3r_ = g2r_*gr - g2i_*gi,     g3i_ = g2r_*gi + g2i_*gr;
    float g4r_ = g2r_*g2r_ - g2i_*g2i_, g4i_ = 2.f*g2r_*g2i_;
    const float G2r = rfl(g2r_), G2i = rfl(g2i_);
    const float G3r = rfl(g3r_), G3i = rfl(g3i_);
    const float G4r = rfl(g4r_), G4i = rfl(g4i_);

    // Mo[k] = g^(16*2^k) k=0..6  (sub-round scan; Mo[6] = g^1024 carry mult)
    float Mor[7], Moi[7];
    {
        const float rl = __expf(-alph * 16.f);
        const float al = th * 16.f;
        float pr = rl * __cosf(al), pq = rl * __sinf(al);
#pragma unroll
        for (int k = 0; k < 7; ++k) {
            Mor[k] = rfl(pr); Moi[k] = rfl(pq);
            const float nr = pr*pr - pq*pq, ni = 2.f*pr*pq;
            pr = nr; pq = ni;
        }
    }
    // Mh[k] = g^(HS*2^k) k=0..5  (halo scan)
    float Mhr[6], Mhi[6];
    {
        const float rl = __expf(-alph * (float)HS);
        const float al = th * (float)HS;
        float pr = rl * __cosf(al), pq = rl * __sinf(al);
#pragma unroll
        for (int k = 0; k < 6; ++k) {
            Mhr[k] = rfl(pr); Mhi[k] = rfl(pq);
            const float nr = pr*pr - pq*pq, ni = 2.f*pr*pq;
            pr = nr; pq = ni;
        }
    }
    // pl = g^(16*lane)
    float plr = 1.f, pli = 0.f;
#pragma unroll
    for (int k = 0; k < 6; ++k) {
        if ((lane >> k) & 1) {
            const float nr = plr*Mor[k] - pli*Moi[k];
            const float ni = plr*Moi[k] + pli*Mor[k];
            plr = nr; pli = ni;
        }
    }

#define LDQ(q) (*(const float4*)&tile[4 * P(q)])
#define DSEL(e0,e1,e2,e3,d0,dn)                                              \
    if constexpr (E == 0)      { e0=d0.x; e1=d0.y; e2=d0.z; e3=d0.w; }       \
    else if constexpr (E == 1) { e0=d0.y; e1=d0.z; e2=d0.w; e3=dn.x; }       \
    else if constexpr (E == 2) { e0=d0.z; e1=d0.w; e2=dn.x; e3=dn.y; }       \
    else                       { e0=d0.w; e1=dn.x; e2=dn.y; e3=dn.z; }
#define STEP(xa, xc)                                              \
    {                                                             \
        const float er = fmaf(-c2, (xc), c1 * (xa));              \
        const float ei = cei * (xc);                              \
        const float nr = fmaf(gr, Br, fmaf(-gi, Bi, er));         \
        const float ni = fmaf(gi, Br, fmaf( gr, Bi, ei));         \
        Br = nr; Bi = ni;                                         \
    }

    const int qpos = 976 + 512 * s;           // quad idx of n0 + s*2048

    // ---------------- own halo: HS samples/lane, total only -----------------
    float Cr, Ci;
    {
        float Br = 0.f, Bi = 0.f;
        const int q1 = qpos - 16 * HS + HQ * lane;   // covers HS*64 lookback
        const int q2 = q1 - QW;                       // >= 3 always
        float4 d0 = LDQ(q2);
#pragma unroll
        for (int m = 0; m < HQ; ++m) {
            const float4 s1 = LDQ(q1 + m);
            const float4 dn = LDQ(q2 + m + 1);
            float e0, e1, e2, e3;
            DSEL(e0, e1, e2, e3, d0, dn);
            STEP(s1.x, e0); STEP(s1.y, e1); STEP(s1.z, e2); STEP(s1.w, e3);
            d0 = dn;
        }
        float Sr = Br, Si = Bi;
#pragma unroll
        for (int k = 0; k < 6; ++k) {
            const int d = 1 << k;
            const float ur = __shfl_up(Sr, d, 64);
            const float ui = __shfl_up(Si, d, 64);
            if (lane >= d) {
                const float nr = fmaf(Mhr[k], ur, fmaf(-Mhi[k], ui, Sr));
                const float ni = fmaf(Mhr[k], ui, fmaf( Mhi[k], ur, Si));
                Sr = nr; Si = ni;
            }
        }
        Cr = rfl(__shfl(Sr, 63, 64));       // state entering n0 + s*2048
        Ci = rfl(__shfl(Si, 63, 64));
    }

    // ---------------- two 1024-sample sub-rounds (16 samples/lane) ----------
#pragma unroll
    for (int ss = 0; ss < 2; ++ss) {
        const int q1 = qpos + 256 * ss + 4 * lane;
        const int q2 = q1 - QW;

        float4 lz[4];
        float Br = 0.f, Bi = 0.f;
        float4 d0 = LDQ(q2);
#pragma unroll
        for (int m = 0; m < 4; ++m) {
            const float4 s1 = LDQ(q1 + m);
            const float4 dn = LDQ(q2 + m + 1);
            float e0, e1, e2, e3;
            DSEL(e0, e1, e2, e3, d0, dn);
            float4 lq;
            STEP(s1.x, e0); lq.x = Bi;
            STEP(s1.y, e1); lq.y = Bi;
            STEP(s1.z, e2); lq.z = Bi;
            STEP(s1.w, e3); lq.w = Bi;
            lz[m] = lq;
            d0 = dn;
        }

        // wave inclusive affine scan (segment mult g^16)
        float Sr = Br, Si = Bi;
#pragma unroll
        for (int k = 0; k < 6; ++k) {
            const int d = 1 << k;
            const float ur = __shfl_up(Sr, d, 64);
            const float ui = __shfl_up(Si, d, 64);
            if (lane >= d) {
                const float nr = fmaf(Mor[k], ur, fmaf(-Moi[k], ui, Sr));
                const float ni = fmaf(Mor[k], ui, fmaf( Moi[k], ur, Si));
                Sr = nr; Si = ni;
            }
        }
        const float Tr = __shfl(Sr, 63, 64);
        const float Ti = __shfl(Si, 63, 64);
        float exr = __shfl_up(Sr, 1, 64);
        float exi = __shfl_up(Si, 1, 64);
        if (lane == 0) { exr = 0.f; exi = 0.f; }

        // exact seed entering this lane's 16-sample segment
        const float sr = fmaf(plr, Cr, fmaf(-pli, Ci, exr));
        const float si = fmaf(plr, Ci, fmaf( pli, Cr, exi));

        // correct + transpose through private ybuf slice (wave-local):
        // lane owns samples [16*lane, 16*lane+16) of THIS 1024-sub-round.
        float wr = fmaf(gr, sr, -(gi * si));    // w = g * seed
        float wi = fmaf(gi, sr,  (gr * si));
#pragma unroll
        for (int m = 0; m < 4; ++m) {
            float4 y;
            y.x = lz[m].x + wi;
            y.y = fmaf(gi,  wr, fmaf(gr,  wi, lz[m].y));
            y.z = fmaf(G2i, wr, fmaf(G2r, wi, lz[m].z));
            y.w = fmaf(G3i, wr, fmaf(G3r, wi, lz[m].w));
            *(float4*)&yw[4 * P(4 * lane + m)] = y;
            const float nwr = fmaf(G4r, wr, -(G4i * wi));
            const float nwi = fmaf(G4i, wr,  (G4r * wi));
            wr = nwr; wi = nwi;
        }
        // per-wave coalesced store (1 KB contiguous per instruction);
        // same-wave LDS write->read: compiler inserts the lgkmcnt wait.
        float* op = out + ((size_t)(b * NO + O)) * (size_t)N_SAMP
                        + n0 + s * 2048 + ss * 1024;
#pragma unroll
        for (int i = 0; i < 4; ++i) {
            const int q = 64 * i + lane;
            const float4 v = *(const float4*)&yw[4 * P(q)];
            *(float4*)(op + 4 * q) = v;
        }

        // carry: C = g^1024 * C + T
        const float nCr = fmaf(Mor[6], Cr, fmaf(-Moi[6], Ci, Tr));
        const float nCi = fmaf(Mor[6], Ci, fmaf( Moi[6], Cr, Ti));
        Cr = rfl(nCr); Ci = rfl(nCi);
    }
#undef STEP
#undef DSEL
#undef LDQ
}

__global__ __launch_bounds__(NT, 4)
void duh_kernel(const float* __restrict__ x, const float* __restrict__ lw,
                float* __restrict__ out)
{
    __shared__ float tile[TQ * 4];            // 32 KB
    __shared__ float ybuf[16 * 1024];         // 64 KB: 4 KB per wave
    const int c  = blockIdx.x;
    const int b  = blockIdx.y;
    const int n0 = c * LBLK;
    const int t  = threadIdx.x;

    // ---- cooperative coalesced stage: [n0-3904, n0+4096) -------------------
    const float* xb = x + (size_t)b * N_SAMP;
    const int tstart = n0 - LOOKB;
#pragma unroll
    for (int i = 0; i < 2; ++i) {
        const int k = t + 1024 * i;
        if (k < TQ) {
            const int g0 = tstart + 4 * k;    // mult of 4; quad fully in/out
            float4 v;
            if (g0 >= 0) v = *(const float4*)(xb + g0);
            else { v.x = 0.f; v.y = 0.f; v.z = 0.f; v.w = 0.f; }
            *(float4*)&tile[4 * P(k)] = v;
        }
    }
    __syncthreads();                           // the ONLY block barrier

    const int wv   = t >> 6;                   // 0..15
    const int o    = wv & 7;
    const int s    = wv >> 3;                  // output half
    const int lane = t & 63;
    float* yw = ybuf + wv * 1024;
    switch (o) {                               // wave (o,s) <-> channel o
      case 0: duh_wave<0>(lw, out, tile, yw, b, n0, s, lane); break;
      case 1: duh_wave<1>(lw, out, tile, yw, b, n0, s, lane); break;
      case 2: duh_wave<2>(lw, out, tile, yw, b, n0, s, lane); break;
      case 3: duh_wave<3>(lw, out, tile, yw, b, n0, s, lane); break;
      case 4: duh_wave<4>(lw, out, tile, yw, b, n0, s, lane); break;
      case 5: duh_wave<5>(lw, out, tile, yw, b, n0, s, lane); break;
      case 6: duh_wave<6>(lw, out, tile, yw, b, n0, s, lane); break;
      default:duh_wave<7>(lw, out, tile, yw, b, n0, s, lane); break;
    }
}

extern "C" void kernel_launch(void* const* d_in, const int* in_sizes, int n_in,
                              void* d_out, int out_size, void* d_ws, size_t ws_size,
                              hipStream_t stream) {
    const float* x  = (const float*)d_in[0];
    const float* lw = (const float*)d_in[1];
    float* out = (float*)d_out;

    dim3 grid(N_SAMP / LBLK, NB);   // 16 chunks x 16 batches = 256 blocks
    duh_kernel<<<grid, dim3(NT), 0, stream>>>(x, lw, out);
}